// Round 8
// baseline (404.601 us; speedup 1.0000x reference)
//
#include <hip/hip_runtime.h>

// RecModel — round 8: DIAGNOSTIC decomposition.
// prep (frags + W0->bf16 + emb gather)  — unlooped.
// hist_kernel ×16 internal loop  -> staged kt=7 slab in ws.   (shows in rocprof)
// comp_kernel ×16 internal loop  -> pure streams+MFMA+fc3.    (shows in rocprof)
// Per-iter asm memory clobber prevents iteration collapse. Numerics == R5/R6.

using u16 = unsigned short;
typedef __attribute__((ext_vector_type(8))) short short8v;
typedef __attribute__((ext_vector_type(4))) short short4v;
typedef __attribute__((ext_vector_type(4))) float floatx4;

constexpr int W1_ELEMS = 13 * 8 * 64 * 8;    // 53248
constexpr int W2_ELEMS = 5 * 7 * 64 * 8;     // 17920
constexpr int W0_ELEMS = 100001 * 16;        // 1600016
constexpr int EF_ELEMS = 1024 * 7 * 64 * 8;  // 3670016
constexpr int NITER = 16;

__device__ __forceinline__ u16 f2bf(float f) {
  unsigned u = __float_as_uint(f);
  unsigned r = (u + 0x7fffu + ((u >> 16) & 1u)) >> 16;  // RN-even
  return (u16)r;
}
__device__ __forceinline__ float bf2f(u16 h) {
  return __uint_as_float(((unsigned)h) << 16);
}

// ---- prep: weight frags + W0 -> bf16 + embedding gather (as round 6) ----
__global__ void prep_kernel(const float* __restrict__ w1, const float* __restrict__ w2,
                            const float* __restrict__ W, const int* __restrict__ sf,
                            u16* __restrict__ w1h, u16* __restrict__ w2h,
                            u16* __restrict__ w0b, u16* __restrict__ ef) {
  int b = blockIdx.x;
  if (b < 35) {
    int tid = b * 256 + threadIdx.x;
    if (tid < 13 * 8 * 64) {
      int l = tid & 63;
      int g = tid >> 6;
      int kt = g & 7, nt = g >> 3;
      int n = nt * 16 + (l & 15);
      int kb = kt * 32 + (l >> 4) * 8;
      short8v h8;
#pragma unroll
      for (int e = 0; e < 8; ++e) {
        int k = kb + e;
        float v = (n < 200 && k < 241) ? w1[n * 241 + k] : 0.f;
        h8[e] = (short)f2bf(v);
      }
      *(short8v*)&w1h[tid * 8] = h8;
    } else if (tid < 13 * 8 * 64 + 5 * 7 * 64) {
      int t2 = tid - 13 * 8 * 64;
      int l = t2 & 63;
      int g = t2 >> 6;
      int kt = g % 7, nt = g / 7;
      int n = nt * 16 + (l & 15);
      int kb = kt * 32 + (l >> 4) * 8;
      short8v h8;
#pragma unroll
      for (int e = 0; e < 8; ++e) {
        int k = kb + e;
        float v = (k < 200) ? w2[n * 200 + k] : 0.f;
        h8[e] = (short)f2bf(v);
      }
      *(short8v*)&w2h[t2 * 8] = h8;
    }
  } else if (b < 35 + 782) {
    int t = (b - 35) * 256 + threadIdx.x;
    int base = t * 8;
    if (base < W0_ELEMS) {
      floatx4 f0 = *(const floatx4*)(W + base);
      floatx4 f1 = *(const floatx4*)(W + base + 4);
      short8v o;
      o[0] = (short)f2bf(f0[0]);
      o[1] = (short)f2bf(f0[1]);
      o[2] = (short)f2bf(f0[2]);
      o[3] = (short)f2bf(f0[3]);
      o[4] = (short)f2bf(f1[0]);
      o[5] = (short)f2bf(f1[1]);
      o[6] = (short)f2bf(f1[2]);
      o[7] = (short)f2bf(f1[3]);
      *(short8v*)(w0b + base) = o;
    }
  } else {
    int g = (b - 817) * 256 + threadIdx.x;  // < 917504
    int t = g >> 16;
    int bb = (g >> 2) & 16383;
    int q = g & 3;
    int idx = sf[bb * 14 + t] + 1;
    floatx4 v4 = *(const floatx4*)(W + ((size_t)t * 100001 + (size_t)idx) * 16 + q * 4);
    short4v h4;
#pragma unroll
    for (int d = 0; d < 4; ++d) h4[d] = (short)f2bf(v4[d]);
    int k0 = t * 16 + q * 4;
    int kt = k0 >> 5, kg = (k0 >> 3) & 3, e0 = k0 & 7;
    int tile = bb >> 4, r = bb & 15;
    *(short4v*)&ef[((tile * 7 + kt) * 64 + kg * 16 + r) * 8 + e0] = h4;
  }
}

// ---- hist_kernel (×NITER): history sums -> kt=7 slab staged in ws ----
// hs layout per tile: [hi: 64 lanes × 8 u16][lo: 64 lanes × 8 u16] = 1024 u16
__global__ __launch_bounds__(256, 4) void hist_kernel(
    const int* __restrict__ hist, const float* __restrict__ dense,
    const u16* __restrict__ w0b, u16* __restrict__ hs) {
  const int tid = threadIdx.x;
  const int tile = blockIdx.x;
  const int row0 = tile * 16;
  short8v z8 = {0, 0, 0, 0, 0, 0, 0, 0};

  for (int it = 0; it < NITER; ++it) {
    int r = tid >> 4, rem = tid & 15, q = rem & 1, s = rem >> 1;
    const int* hp = hist + (row0 + r) * 50;
    const u16* Wq = w0b + q * 8;
    float a[8] = {0.f, 0.f, 0.f, 0.f, 0.f, 0.f, 0.f, 0.f};
#pragma unroll
    for (int hh = 0; hh < 6; ++hh) {  // h = s + 8*hh
      int idx = hp[s + hh * 8] + 1;
      short8v v = *(const short8v*)(Wq + (size_t)idx * 16);
#pragma unroll
      for (int d = 0; d < 8; ++d) a[d] += bf2f((u16)v[d]);
    }
    if (s < 2) {  // tail h = 48+s
      int idx = hp[48 + s] + 1;
      short8v v = *(const short8v*)(Wq + (size_t)idx * 16);
#pragma unroll
      for (int d = 0; d < 8; ++d) a[d] += bf2f((u16)v[d]);
    }
#pragma unroll
    for (int d = 0; d < 8; ++d) {
      a[d] += __shfl_xor(a[d], 2);
      a[d] += __shfl_xor(a[d], 4);
      a[d] += __shfl_xor(a[d], 8);
    }
    if (s == 0) {
      short8v h8, l8;
#pragma unroll
      for (int d = 0; d < 8; ++d) {
        u16 hi = f2bf(a[d]);
        h8[d] = (short)hi;
        l8[d] = (short)f2bf(a[d] - bf2f(hi));
      }
      u16* ht = hs + tile * 1024;
      *(short8v*)&ht[(q * 16 + r) * 8] = h8;
      *(short8v*)&ht[512 + (q * 16 + r) * 8] = l8;
      if (q == 0) {
        float dv = dense[row0 + r];
        u16 dh = f2bf(dv), dl = f2bf(dv - bf2f(dh));
        short8v dh8 = z8, dl8 = z8;
        dh8[0] = (short)dh;
        dl8[0] = (short)dl;
        *(short8v*)&ht[(32 + r) * 8] = dh8;
        *(short8v*)&ht[512 + (32 + r) * 8] = dl8;
        *(short8v*)&ht[(48 + r) * 8] = z8;
        *(short8v*)&ht[512 + (48 + r) * 8] = z8;
      }
    }
    asm volatile("" ::: "memory");  // keep iterations independent & live
  }
}

// ---- comp_kernel (×NITER): pure streaming MLP ----
__global__ __launch_bounds__(256, 4) void comp_kernel(
    const u16* __restrict__ ef, const u16* __restrict__ hs,
    const u16* __restrict__ w1h, const u16* __restrict__ w2h,
    const float* __restrict__ b1, const float* __restrict__ b2,
    const float* __restrict__ w3, const float* __restrict__ b3,
    float* __restrict__ out) {
  __shared__ u16 A2h[7 * 64 * 8], A2l[7 * 64 * 8];
  __shared__ float o2[16 * 84];

  const int tid = threadIdx.x;
  const int l = tid & 63;
  const int wv = tid >> 6;
  const int tile = blockIdx.x;
  const int row0 = tile * 16;
  short8v z8 = {0, 0, 0, 0, 0, 0, 0, 0};
  const int ntbase = (wv == 0) ? 0 : 4 + 3 * (wv - 1);
  const int ntcnt = (wv == 0) ? 4 : 3;

  for (int it = 0; it < NITER; ++it) {
    // A fragments: kt 0..6 stream from ef, kt=7 hi/lo from hs
    short8v ga[7];
#pragma unroll
    for (int kt = 0; kt < 7; ++kt)
      ga[kt] = *(const short8v*)&ef[((tile * 7 + kt) * 64 + l) * 8];
    short8v a7h = *(const short8v*)&hs[tile * 1024 + l * 8];
    short8v a7l = *(const short8v*)&hs[tile * 1024 + 512 + l * 8];

    short8v bhr[2][4];
#pragma unroll
    for (int kk = 0; kk < 2; ++kk)
#pragma unroll
      for (int i = 0; i < 4; ++i)
        bhr[kk][i] = (i < ntcnt) ? *(const short8v*)&w1h[(((ntbase + i) * 8 + kk) * 64 + l) * 8]
                                 : z8;

    floatx4 acc[4];
#pragma unroll
    for (int i = 0; i < 4; ++i) acc[i] = (floatx4){0.f, 0.f, 0.f, 0.f};

#pragma unroll
    for (int kt = 0; kt < 8; ++kt) {
      short8v ah = (kt < 7) ? ga[kt] : a7h;
#pragma unroll
      for (int i = 0; i < 4; ++i) {
        if (i < ntcnt) {
          short8v cb = bhr[kt & 1][i];
          if (kt < 6) bhr[kt & 1][i] = *(const short8v*)&w1h[(((ntbase + i) * 8 + kt + 2) * 64 + l) * 8];
          acc[i] = __builtin_amdgcn_mfma_f32_16x16x32_bf16(ah, cb, acc[i], 0, 0, 0);
          if (kt == 7) acc[i] = __builtin_amdgcn_mfma_f32_16x16x32_bf16(a7l, cb, acc[i], 0, 0, 0);
        }
      }
    }

    const int ntA = wv;
    short8v bra[2], brb[2];
    bra[0] = *(const short8v*)&w2h[((ntA * 7 + 0) * 64 + l) * 8];
    bra[1] = *(const short8v*)&w2h[((ntA * 7 + 1) * 64 + l) * 8];
    if (wv == 0) {
      brb[0] = *(const short8v*)&w2h[((4 * 7 + 0) * 64 + l) * 8];
      brb[1] = *(const short8v*)&w2h[((4 * 7 + 1) * 64 + l) * 8];
    } else {
      brb[0] = z8;
      brb[1] = z8;
    }

#pragma unroll
    for (int i = 0; i < 4; ++i) {
      if (i < ntcnt) {
        int n = (ntbase + i) * 16 + (l & 15);
        float bias = (n < 200) ? b1[n] : 0.f;
#pragma unroll
        for (int g = 0; g < 4; ++g) {
          float v = (n < 200) ? fmaxf(acc[i][g] + bias, 0.f) : 0.f;
          int m = (l >> 4) * 4 + g;
          u16 hi = f2bf(v), lo = f2bf(v - bf2f(hi));
          int kt2 = n >> 5, kg2 = (n >> 3) & 3, e = n & 7;
          int pos = (kt2 * 64 + kg2 * 16 + m) * 8 + e;
          A2h[pos] = hi;
          A2l[pos] = lo;
        }
      }
    }
    if (wv == 1 && l < 32) {
      *(short8v*)&A2h[(6 * 64 + 32 + l) * 8] = z8;
      *(short8v*)&A2l[(6 * 64 + 32 + l) * 8] = z8;
    }
    __syncthreads();  // A2 complete

    floatx4 acca = (floatx4){0.f, 0.f, 0.f, 0.f};
    floatx4 accb = (floatx4){0.f, 0.f, 0.f, 0.f};
#pragma unroll
    for (int kt = 0; kt < 7; ++kt) {
      short8v ah = *(const short8v*)&A2h[(kt * 64 + l) * 8];
      short8v al = *(const short8v*)&A2l[(kt * 64 + l) * 8];
      short8v ca = bra[kt & 1];
      if (kt < 5) bra[kt & 1] = *(const short8v*)&w2h[((ntA * 7 + kt + 2) * 64 + l) * 8];
      acca = __builtin_amdgcn_mfma_f32_16x16x32_bf16(ah, ca, acca, 0, 0, 0);
      acca = __builtin_amdgcn_mfma_f32_16x16x32_bf16(al, ca, acca, 0, 0, 0);
      if (wv == 0) {
        short8v cb = brb[kt & 1];
        if (kt < 5) brb[kt & 1] = *(const short8v*)&w2h[((4 * 7 + kt + 2) * 64 + l) * 8];
        accb = __builtin_amdgcn_mfma_f32_16x16x32_bf16(ah, cb, accb, 0, 0, 0);
        accb = __builtin_amdgcn_mfma_f32_16x16x32_bf16(al, cb, accb, 0, 0, 0);
      }
    }

    {
      int n = ntA * 16 + (l & 15);
      float bias = b2[n];
#pragma unroll
      for (int g = 0; g < 4; ++g) {
        int r = (l >> 4) * 4 + g;
        o2[r * 84 + n] = fmaxf(acca[g] + bias, 0.f);
      }
      if (wv == 0) {
        int n2 = 64 + (l & 15);
        float bias2 = b2[n2];
#pragma unroll
        for (int g = 0; g < 4; ++g) {
          int r = (l >> 4) * 4 + g;
          o2[r * 84 + n2] = fmaxf(accb[g] + bias2, 0.f);
        }
      }
    }
    __syncthreads();  // o2 complete

    if (tid < 32) {
      int r = tid >> 1, o = tid & 1;
      float a = b3[o];
      const float* orow = &o2[r * 84];
      const float* wrow = &w3[o * 80];
#pragma unroll
      for (int j = 0; j < 80; j += 4) {
        floatx4 xv = *(const floatx4*)&orow[j];
        floatx4 wv4 = *(const floatx4*)&wrow[j];
        a += xv[0] * wv4[0] + xv[1] * wv4[1] + xv[2] * wv4[2] + xv[3] * wv4[3];
      }
      out[(row0 + r) * 2 + o] = a;
    }
    __syncthreads();  // safe LDS reuse across iterations
    asm volatile("" ::: "memory");  // keep iterations independent & live
  }
}

extern "C" void kernel_launch(void* const* d_in, const int* in_sizes, int n_in,
                              void* d_out, int out_size, void* d_ws, size_t ws_size,
                              hipStream_t stream) {
  const int* sf = (const int*)d_in[0];
  const float* dense = (const float*)d_in[1];
  const int* hist = (const int*)d_in[2];
  const float* W = (const float*)d_in[3];
  const float* w1 = (const float*)d_in[4];
  const float* b1 = (const float*)d_in[5];
  const float* w2 = (const float*)d_in[6];
  const float* b2 = (const float*)d_in[7];
  const float* w3 = (const float*)d_in[8];
  const float* b3 = (const float*)d_in[9];
  float* out = (float*)d_out;

  u16* w1h = (u16*)d_ws;
  u16* w2h = w1h + W1_ELEMS;
  u16* w0b = w2h + W2_ELEMS;
  u16* ef = w0b + W0_ELEMS;
  u16* hs = ef + EF_ELEMS;  // 1024 tiles × 1024 u16 = 2 MB

  prep_kernel<<<dim3(35 + 782 + 3584), dim3(256), 0, stream>>>(w1, w2, W, sf, w1h, w2h, w0b, ef);
  hist_kernel<<<dim3(1024), dim3(256), 0, stream>>>(hist, dense, w0b, hs);
  comp_kernel<<<dim3(1024), dim3(256), 0, stream>>>(ef, hs, w1h, w2h, b1, b2, w3, b3, out);
}

// Round 9
// 37.015 us; speedup vs baseline: 10.9307x; 10.9307x over previous
//
#include <hip/hip_runtime.h>

// RecModel — round 9. Diagnostic (R8) showed comp = 23µs of the 30µs total
// (weight re-streaming with ~1 MFMA per load, latency-exposed), hist < 3.2µs.
// Fix: 64-row comp blocks (grid 256 = 1/CU) -> 4 MFMAs per weight load, weight
// traffic /4, fat ILP. hist moved into prep (fp32 W, no w0b conversion).

using u16 = unsigned short;
typedef __attribute__((ext_vector_type(8))) short short8v;
typedef __attribute__((ext_vector_type(4))) short short4v;
typedef __attribute__((ext_vector_type(4))) float floatx4;

constexpr int W1_ELEMS = 13 * 8 * 64 * 8;    // 53248
constexpr int W2_ELEMS = 5 * 7 * 64 * 8;     // 17920
constexpr int EF_ELEMS = 1024 * 7 * 64 * 8;  // 3670016
constexpr int HS_ELEMS = 1024 * 1024;        // per tile: 512 u16 hi + 512 u16 lo

__device__ __forceinline__ u16 f2bf(float f) {
  unsigned u = __float_as_uint(f);
  unsigned r = (u + 0x7fffu + ((u >> 16) & 1u)) >> 16;  // RN-even
  return (u16)r;
}
__device__ __forceinline__ float bf2f(u16 h) {
  return __uint_as_float(((unsigned)h) << 16);
}

// ---- prep: [0,35) weight frags | [35,3619) emb gather | [3619,4643) history ----
__global__ __launch_bounds__(256) void prep_kernel(
    const float* __restrict__ w1, const float* __restrict__ w2,
    const float* __restrict__ W, const int* __restrict__ sf,
    const int* __restrict__ hist, const float* __restrict__ dense,
    u16* __restrict__ w1h, u16* __restrict__ w2h,
    u16* __restrict__ ef, u16* __restrict__ hs) {
  const int b = blockIdx.x;
  const int tix = threadIdx.x;
  short8v z8 = {0, 0, 0, 0, 0, 0, 0, 0};

  if (b < 35) {
    int tid = b * 256 + tix;
    if (tid < 13 * 8 * 64) {  // fc1 frags
      int l = tid & 63;
      int g = tid >> 6;
      int kt = g & 7, nt = g >> 3;
      int n = nt * 16 + (l & 15);
      int kb = kt * 32 + (l >> 4) * 8;
      short8v h8;
#pragma unroll
      for (int e = 0; e < 8; ++e) {
        int k = kb + e;
        float v = (n < 200 && k < 241) ? w1[n * 241 + k] : 0.f;
        h8[e] = (short)f2bf(v);
      }
      *(short8v*)&w1h[tid * 8] = h8;
    } else if (tid < 13 * 8 * 64 + 5 * 7 * 64) {  // fc2 frags
      int t2 = tid - 13 * 8 * 64;
      int l = t2 & 63;
      int g = t2 >> 6;
      int kt = g % 7, nt = g / 7;
      int n = nt * 16 + (l & 15);
      int kb = kt * 32 + (l >> 4) * 8;
      short8v h8;
#pragma unroll
      for (int e = 0; e < 8; ++e) {
        int k = kb + e;
        float v = (k < 200) ? w2[n * 200 + k] : 0.f;
        h8[e] = (short)f2bf(v);
      }
      *(short8v*)&w2h[t2 * 8] = h8;
    }
  } else if (b < 3619) {
    // embedding gather: one thread per (t, batch, q)
    int g = (b - 35) * 256 + tix;  // < 917504
    int t = g >> 16;
    int bb = (g >> 2) & 16383;
    int q = g & 3;
    int idx = sf[bb * 14 + t] + 1;  // [1,100000]
    floatx4 v4 = *(const floatx4*)(W + ((size_t)t * 100001 + (size_t)idx) * 16 + q * 4);
    short4v h4;
#pragma unroll
    for (int d = 0; d < 4; ++d) h4[d] = (short)f2bf(v4[d]);
    int k0 = t * 16 + q * 4;  // kt 0..6
    int kt = k0 >> 5, kg = (k0 >> 3) & 3, e0 = k0 & 7;
    int tile = bb >> 4, r = bb & 15;
    *(short4v*)&ef[((tile * 7 + kt) * 64 + kg * 16 + r) * 8 + e0] = h4;
  } else {
    // history: 16 thr/row (q dim-quad x s 4-way split), fp32 W, 16 rows/block
    int tile = b - 3619;
    int row0 = tile * 16;
    int r = tix >> 4, rem = tix & 15, q = rem & 3, s = rem >> 2;
    const int* hp = hist + (row0 + r) * 50;
    float a0 = 0.f, a1 = 0.f, a2 = 0.f, a3 = 0.f;
#pragma unroll
    for (int hh = 0; hh < 12; ++hh) {  // h = s + 4*hh (constant trip)
      int idx = hp[s + hh * 4] + 1;    // row 0 never hit
      floatx4 p = *(const floatx4*)(W + (size_t)idx * 16 + q * 4);
      a0 += p[0];
      a1 += p[1];
      a2 += p[2];
      a3 += p[3];
    }
    if (s < 2) {  // tail h = 48+s
      int idx = hp[48 + s] + 1;
      floatx4 p = *(const floatx4*)(W + (size_t)idx * 16 + q * 4);
      a0 += p[0];
      a1 += p[1];
      a2 += p[2];
      a3 += p[3];
    }
    a0 += __shfl_xor(a0, 4);
    a1 += __shfl_xor(a1, 4);
    a2 += __shfl_xor(a2, 4);
    a3 += __shfl_xor(a3, 4);
    a0 += __shfl_xor(a0, 8);
    a1 += __shfl_xor(a1, 8);
    a2 += __shfl_xor(a2, 8);
    a3 += __shfl_xor(a3, 8);
    if (s == 0) {
      float vals[4] = {a0, a1, a2, a3};
      short4v h4, l4;
#pragma unroll
      for (int d = 0; d < 4; ++d) {
        u16 hi = f2bf(vals[d]);
        h4[d] = (short)hi;
        l4[d] = (short)f2bf(vals[d] - bf2f(hi));
      }
      u16* ht = hs + (size_t)tile * 1024;
      // k = 224 + q*4 + d -> frag lane (q>>1)*16 + r, elem (q*4)&7
      int base = ((q >> 1) * 16 + r) * 8 + ((q * 4) & 7);
      *(short4v*)&ht[base] = h4;
      *(short4v*)&ht[512 + base] = l4;
      if (q == 0) {
        float dv = dense[row0 + r];
        u16 dh = f2bf(dv), dl = f2bf(dv - bf2f(dh));
        short8v dh8 = z8, dl8 = z8;
        dh8[0] = (short)dh;
        dl8[0] = (short)dl;
        *(short8v*)&ht[(32 + r) * 8] = dh8;         // k 240..247 (dense + pad)
        *(short8v*)&ht[512 + (32 + r) * 8] = dl8;
        *(short8v*)&ht[(48 + r) * 8] = z8;          // k 248..255 zero
        *(short8v*)&ht[512 + (48 + r) * 8] = z8;
      }
    }
  }
}

// ---- mlp: 256 blocks x 256 thr (1/CU), 64 rows/block = 4 subtiles ----
__global__ __launch_bounds__(256, 1) void mlp_kernel(
    const u16* __restrict__ ef, const u16* __restrict__ hs,
    const u16* __restrict__ w1h, const u16* __restrict__ w2h,
    const float* __restrict__ b1, const float* __restrict__ b2,
    const float* __restrict__ w3, const float* __restrict__ b3,
    float* __restrict__ out) {
  __shared__ u16 A2h[4 * 7 * 64 * 8], A2l[4 * 7 * 64 * 8];  // 28KB + 28KB
  __shared__ float o2[64 * 84];                             // 21KB

  const int tid = threadIdx.x;
  const int l = tid & 63;
  const int wv = tid >> 6;
  const int blk = blockIdx.x;
  const int row0 = blk * 64;
  short8v z8 = {0, 0, 0, 0, 0, 0, 0, 0};
  const int ntbase = (wv == 0) ? 0 : 4 + 3 * (wv - 1);
  const int ntcnt = (wv == 0) ? 4 : 3;

  // kt=7 A-frags straight from global (issue early; used last)
  short8v a7h[4], a7l[4];
#pragma unroll
  for (int sub = 0; sub < 4; ++sub) {
    const u16* ht = hs + (size_t)(blk * 4 + sub) * 1024;
    a7h[sub] = *(const short8v*)&ht[l * 8];
    a7l[sub] = *(const short8v*)&ht[512 + l * 8];
  }
  // A-frag (ef) depth-2 prefetch
  short8v ga[2][4];
#pragma unroll
  for (int kk = 0; kk < 2; ++kk)
#pragma unroll
    for (int sub = 0; sub < 4; ++sub)
      ga[kk][sub] = *(const short8v*)&ef[(((blk * 4 + sub) * 7 + kk) * 64 + l) * 8];
  // B depth-2 prefetch
  short8v bhr[2][4];
#pragma unroll
  for (int kk = 0; kk < 2; ++kk)
#pragma unroll
    for (int i = 0; i < 4; ++i)
      bhr[kk][i] = (i < ntcnt) ? *(const short8v*)&w1h[(((ntbase + i) * 8 + kk) * 64 + l) * 8]
                               : z8;

  // ---- GEMM1: per kt-step, 16-17 MFMAs per wave (4 subtiles per weight load) ----
  floatx4 acc[4][4];
#pragma unroll
  for (int i = 0; i < 4; ++i)
#pragma unroll
    for (int sub = 0; sub < 4; ++sub) acc[i][sub] = (floatx4){0.f, 0.f, 0.f, 0.f};

#pragma unroll
  for (int kt = 0; kt < 8; ++kt) {
    const int cur = kt & 1;
    short8v a_[4];
#pragma unroll
    for (int sub = 0; sub < 4; ++sub) a_[sub] = (kt < 7) ? ga[cur][sub] : a7h[sub];
    if (kt < 5) {  // prefetch ef kt+2
#pragma unroll
      for (int sub = 0; sub < 4; ++sub)
        ga[cur][sub] = *(const short8v*)&ef[(((blk * 4 + sub) * 7 + kt + 2) * 64 + l) * 8];
    }
#pragma unroll
    for (int i = 0; i < 4; ++i) {
      if (i < ntcnt) {
        short8v cb = bhr[cur][i];
        if (kt < 6)
          bhr[cur][i] = *(const short8v*)&w1h[(((ntbase + i) * 8 + kt + 2) * 64 + l) * 8];
#pragma unroll
        for (int sub = 0; sub < 4; ++sub) {
          acc[i][sub] = __builtin_amdgcn_mfma_f32_16x16x32_bf16(a_[sub], cb, acc[i][sub], 0, 0, 0);
          if (kt == 7)
            acc[i][sub] = __builtin_amdgcn_mfma_f32_16x16x32_bf16(a7l[sub], cb, acc[i][sub], 0, 0, 0);
        }
      }
    }
  }

  // GEMM2 B prefetch: wave w -> nt2=w; wave1 also nt2=4
  const int ntA = wv;
  const bool dual = (wv == 1);
  short8v bra[2], brb[2];
  bra[0] = *(const short8v*)&w2h[((ntA * 7 + 0) * 64 + l) * 8];
  bra[1] = *(const short8v*)&w2h[((ntA * 7 + 1) * 64 + l) * 8];
  brb[0] = dual ? *(const short8v*)&w2h[((4 * 7 + 0) * 64 + l) * 8] : z8;
  brb[1] = dual ? *(const short8v*)&w2h[((4 * 7 + 1) * 64 + l) * 8] : z8;

  // ---- epilogue1: bias+relu -> A2 frags (hi/lo), all 4 subtiles ----
#pragma unroll
  for (int i = 0; i < 4; ++i) {
    if (i < ntcnt) {
      int n = (ntbase + i) * 16 + (l & 15);
      float bias = (n < 200) ? b1[n] : 0.f;
      int kt2 = n >> 5, kg2 = (n >> 3) & 3, e = n & 7;
#pragma unroll
      for (int sub = 0; sub < 4; ++sub) {
#pragma unroll
        for (int g = 0; g < 4; ++g) {
          float v = (n < 200) ? fmaxf(acc[i][sub][g] + bias, 0.f) : 0.f;
          int m = (l >> 4) * 4 + g;
          u16 hi = f2bf(v), lo = f2bf(v - bf2f(hi));
          int pos = ((sub * 7 + kt2) * 64 + kg2 * 16 + m) * 8 + e;
          A2h[pos] = hi;
          A2l[pos] = lo;
        }
      }
    }
  }
  if (wv == 1 && l < 32) {  // zero k2 in [208,224) for all subtiles
#pragma unroll
    for (int sub = 0; sub < 4; ++sub) {
      *(short8v*)&A2h[((sub * 7 + 6) * 64 + 32 + l) * 8] = z8;
      *(short8v*)&A2l[((sub * 7 + 6) * 64 + 32 + l) * 8] = z8;
    }
  }
  __syncthreads();  // A2 complete

  // ---- GEMM2: 8-16 MFMAs per weight load ----
  floatx4 acc2a[4], acc2b[4];
#pragma unroll
  for (int sub = 0; sub < 4; ++sub) {
    acc2a[sub] = (floatx4){0.f, 0.f, 0.f, 0.f};
    acc2b[sub] = (floatx4){0.f, 0.f, 0.f, 0.f};
  }
#pragma unroll
  for (int kt = 0; kt < 7; ++kt) {
    short8v ca = bra[kt & 1];
    if (kt < 5) bra[kt & 1] = *(const short8v*)&w2h[((ntA * 7 + kt + 2) * 64 + l) * 8];
    short8v cb2 = brb[kt & 1];
    if (dual && kt < 5) brb[kt & 1] = *(const short8v*)&w2h[((4 * 7 + kt + 2) * 64 + l) * 8];
#pragma unroll
    for (int sub = 0; sub < 4; ++sub) {
      short8v ah = *(const short8v*)&A2h[((sub * 7 + kt) * 64 + l) * 8];
      short8v al = *(const short8v*)&A2l[((sub * 7 + kt) * 64 + l) * 8];
      acc2a[sub] = __builtin_amdgcn_mfma_f32_16x16x32_bf16(ah, ca, acc2a[sub], 0, 0, 0);
      acc2a[sub] = __builtin_amdgcn_mfma_f32_16x16x32_bf16(al, ca, acc2a[sub], 0, 0, 0);
      if (dual) {
        acc2b[sub] = __builtin_amdgcn_mfma_f32_16x16x32_bf16(ah, cb2, acc2b[sub], 0, 0, 0);
        acc2b[sub] = __builtin_amdgcn_mfma_f32_16x16x32_bf16(al, cb2, acc2b[sub], 0, 0, 0);
      }
    }
  }

  // ---- epilogue2: bias+relu -> o2 [64][84] ----
  {
    int n = ntA * 16 + (l & 15);
    float bias = b2[n];
#pragma unroll
    for (int sub = 0; sub < 4; ++sub)
#pragma unroll
      for (int g = 0; g < 4; ++g) {
        int r2 = sub * 16 + (l >> 4) * 4 + g;
        o2[r2 * 84 + n] = fmaxf(acc2a[sub][g] + bias, 0.f);
      }
    if (dual) {
      int n2 = 64 + (l & 15);
      float bias2 = b2[n2];
#pragma unroll
      for (int sub = 0; sub < 4; ++sub)
#pragma unroll
        for (int g = 0; g < 4; ++g) {
          int r2 = sub * 16 + (l >> 4) * 4 + g;
          o2[r2 * 84 + n2] = fmaxf(acc2b[sub][g] + bias2, 0.f);
        }
    }
  }
  __syncthreads();  // o2 complete

  // ---- fc3: 128 threads, one (row, out) pair each ----
  if (tid < 128) {
    int r = tid >> 1, o = tid & 1;
    float a = b3[o];
    const float* orow = &o2[r * 84];
    const float* wrow = &w3[o * 80];
#pragma unroll
    for (int j = 0; j < 80; j += 4) {
      floatx4 xv = *(const floatx4*)&orow[j];
      floatx4 wv4 = *(const floatx4*)&wrow[j];
      a += xv[0] * wv4[0] + xv[1] * wv4[1] + xv[2] * wv4[2] + xv[3] * wv4[3];
    }
    out[(row0 + r) * 2 + o] = a;
  }
}

extern "C" void kernel_launch(void* const* d_in, const int* in_sizes, int n_in,
                              void* d_out, int out_size, void* d_ws, size_t ws_size,
                              hipStream_t stream) {
  const int* sf = (const int*)d_in[0];
  const float* dense = (const float*)d_in[1];
  const int* hist = (const int*)d_in[2];
  const float* W = (const float*)d_in[3];
  const float* w1 = (const float*)d_in[4];
  const float* b1 = (const float*)d_in[5];
  const float* w2 = (const float*)d_in[6];
  const float* b2 = (const float*)d_in[7];
  const float* w3 = (const float*)d_in[8];
  const float* b3 = (const float*)d_in[9];
  float* out = (float*)d_out;

  u16* w1h = (u16*)d_ws;
  u16* w2h = w1h + W1_ELEMS;
  u16* ef = w2h + W2_ELEMS;
  u16* hs = ef + EF_ELEMS;  // 2 MB

  prep_kernel<<<dim3(35 + 3584 + 1024), dim3(256), 0, stream>>>(
      w1, w2, W, sf, hist, dense, w1h, w2h, ef, hs);
  mlp_kernel<<<dim3(256), dim3(256), 0, stream>>>(ef, hs, w1h, w2h, b1, b2, w3, b3, out);
}

// Round 10
// 35.259 us; speedup vs baseline: 11.4751x; 1.0498x over previous
//
#include <hip/hip_runtime.h>

// RecModel — round 10. Model: mlp is concurrency-limited load throughput
// (~10 B/cyc/CU). Fix: 64-row blocks with 16 waves (1024 thr) — weight reuse
// (4 subtiles per B-frag, L1-dedup across same-ntg waves) AND full TLP.
// prep identical to R9. Numerics identical (absmax 7.32e-4 expected).

using u16 = unsigned short;
typedef __attribute__((ext_vector_type(8))) short short8v;
typedef __attribute__((ext_vector_type(4))) short short4v;
typedef __attribute__((ext_vector_type(4))) float floatx4;

constexpr int W1_ELEMS = 13 * 8 * 64 * 8;    // 53248
constexpr int W2_ELEMS = 5 * 7 * 64 * 8;     // 17920
constexpr int EF_ELEMS = 1024 * 7 * 64 * 8;  // 3670016

__device__ __forceinline__ u16 f2bf(float f) {
  unsigned u = __float_as_uint(f);
  unsigned r = (u + 0x7fffu + ((u >> 16) & 1u)) >> 16;  // RN-even
  return (u16)r;
}
__device__ __forceinline__ float bf2f(u16 h) {
  return __uint_as_float(((unsigned)h) << 16);
}

// ---- prep: [0,35) weight frags | [35,3619) emb gather | [3619,4643) history ----
__global__ __launch_bounds__(256) void prep_kernel(
    const float* __restrict__ w1, const float* __restrict__ w2,
    const float* __restrict__ W, const int* __restrict__ sf,
    const int* __restrict__ hist, const float* __restrict__ dense,
    u16* __restrict__ w1h, u16* __restrict__ w2h,
    u16* __restrict__ ef, u16* __restrict__ hs) {
  const int b = blockIdx.x;
  const int tix = threadIdx.x;
  short8v z8 = {0, 0, 0, 0, 0, 0, 0, 0};

  if (b < 35) {
    int tid = b * 256 + tix;
    if (tid < 13 * 8 * 64) {  // fc1 frags
      int l = tid & 63;
      int g = tid >> 6;
      int kt = g & 7, nt = g >> 3;
      int n = nt * 16 + (l & 15);
      int kb = kt * 32 + (l >> 4) * 8;
      short8v h8;
#pragma unroll
      for (int e = 0; e < 8; ++e) {
        int k = kb + e;
        float v = (n < 200 && k < 241) ? w1[n * 241 + k] : 0.f;
        h8[e] = (short)f2bf(v);
      }
      *(short8v*)&w1h[tid * 8] = h8;
    } else if (tid < 13 * 8 * 64 + 5 * 7 * 64) {  // fc2 frags
      int t2 = tid - 13 * 8 * 64;
      int l = t2 & 63;
      int g = t2 >> 6;
      int kt = g % 7, nt = g / 7;
      int n = nt * 16 + (l & 15);
      int kb = kt * 32 + (l >> 4) * 8;
      short8v h8;
#pragma unroll
      for (int e = 0; e < 8; ++e) {
        int k = kb + e;
        float v = (k < 200) ? w2[n * 200 + k] : 0.f;
        h8[e] = (short)f2bf(v);
      }
      *(short8v*)&w2h[t2 * 8] = h8;
    }
  } else if (b < 3619) {
    // embedding gather: one thread per (t, batch, q)
    int g = (b - 35) * 256 + tix;  // < 917504
    int t = g >> 16;
    int bb = (g >> 2) & 16383;
    int q = g & 3;
    int idx = sf[bb * 14 + t] + 1;  // [1,100000]
    floatx4 v4 = *(const floatx4*)(W + ((size_t)t * 100001 + (size_t)idx) * 16 + q * 4);
    short4v h4;
#pragma unroll
    for (int d = 0; d < 4; ++d) h4[d] = (short)f2bf(v4[d]);
    int k0 = t * 16 + q * 4;  // kt 0..6
    int kt = k0 >> 5, kg = (k0 >> 3) & 3, e0 = k0 & 7;
    int tile = bb >> 4, r = bb & 15;
    *(short4v*)&ef[((tile * 7 + kt) * 64 + kg * 16 + r) * 8 + e0] = h4;
  } else {
    // history: 16 thr/row (q dim-quad x s 4-way split), fp32 W, 16 rows/block
    int tile = b - 3619;
    int row0 = tile * 16;
    int r = tix >> 4, rem = tix & 15, q = rem & 3, s = rem >> 2;
    const int* hp = hist + (row0 + r) * 50;
    float a0 = 0.f, a1 = 0.f, a2 = 0.f, a3 = 0.f;
#pragma unroll
    for (int hh = 0; hh < 12; ++hh) {  // h = s + 4*hh (constant trip)
      int idx = hp[s + hh * 4] + 1;    // row 0 never hit
      floatx4 p = *(const floatx4*)(W + (size_t)idx * 16 + q * 4);
      a0 += p[0];
      a1 += p[1];
      a2 += p[2];
      a3 += p[3];
    }
    if (s < 2) {  // tail h = 48+s
      int idx = hp[48 + s] + 1;
      floatx4 p = *(const floatx4*)(W + (size_t)idx * 16 + q * 4);
      a0 += p[0];
      a1 += p[1];
      a2 += p[2];
      a3 += p[3];
    }
    a0 += __shfl_xor(a0, 4);
    a1 += __shfl_xor(a1, 4);
    a2 += __shfl_xor(a2, 4);
    a3 += __shfl_xor(a3, 4);
    a0 += __shfl_xor(a0, 8);
    a1 += __shfl_xor(a1, 8);
    a2 += __shfl_xor(a2, 8);
    a3 += __shfl_xor(a3, 8);
    if (s == 0) {
      float vals[4] = {a0, a1, a2, a3};
      short4v h4, l4;
#pragma unroll
      for (int d = 0; d < 4; ++d) {
        u16 hi = f2bf(vals[d]);
        h4[d] = (short)hi;
        l4[d] = (short)f2bf(vals[d] - bf2f(hi));
      }
      u16* ht = hs + (size_t)tile * 1024;
      int base = ((q >> 1) * 16 + r) * 8 + ((q * 4) & 7);
      *(short4v*)&ht[base] = h4;
      *(short4v*)&ht[512 + base] = l4;
      if (q == 0) {
        float dv = dense[row0 + r];
        u16 dh = f2bf(dv), dl = f2bf(dv - bf2f(dh));
        short8v dh8 = z8, dl8 = z8;
        dh8[0] = (short)dh;
        dl8[0] = (short)dl;
        *(short8v*)&ht[(32 + r) * 8] = dh8;  // k 240..247 (dense + pad)
        *(short8v*)&ht[512 + (32 + r) * 8] = dl8;
        *(short8v*)&ht[(48 + r) * 8] = z8;   // k 248..255 zero
        *(short8v*)&ht[512 + (48 + r) * 8] = z8;
      }
    }
  }
}

// ---- mlp: 256 blocks x 1024 thr (16 waves/CU); wave = (sub, ntg) ----
__global__ __launch_bounds__(1024, 4) void mlp_kernel(
    const u16* __restrict__ ef, const u16* __restrict__ hs,
    const u16* __restrict__ w1h, const u16* __restrict__ w2h,
    const float* __restrict__ b1, const float* __restrict__ b2,
    const float* __restrict__ w3, const float* __restrict__ b3,
    float* __restrict__ out) {
  __shared__ u16 A2h[4 * 7 * 64 * 8], A2l[4 * 7 * 64 * 8];  // 28KB + 28KB
  __shared__ float o2[64 * 84];                             // 21KB

  const int tid = threadIdx.x;
  const int l = tid & 63;
  const int w = tid >> 6;   // 0..15
  const int sub = w & 3;    // row subtile (16 rows)
  const int ntg = w >> 2;   // nt group
  const int blk = blockIdx.x;
  const int tile = blk * 4 + sub;
  const int row0 = blk * 64;
  short8v z8 = {0, 0, 0, 0, 0, 0, 0, 0};
  const int ntbase = (ntg == 0) ? 0 : 4 + 3 * (ntg - 1);
  const int ntcnt = (ntg == 0) ? 4 : 3;

  // kt=7 A-frags from hs (issue early)
  const u16* ht = hs + (size_t)tile * 1024;
  short8v a7h = *(const short8v*)&ht[l * 8];
  short8v a7l = *(const short8v*)&ht[512 + l * 8];

  // ef depth-2 prefetch (own subtile only)
  short8v ga[2];
  ga[0] = *(const short8v*)&ef[((tile * 7 + 0) * 64 + l) * 8];
  ga[1] = *(const short8v*)&ef[((tile * 7 + 1) * 64 + l) * 8];

  // B depth-2 prefetch (own ntg; same addrs as sibling subs -> L1 dedup)
  short8v bhr[2][4];
#pragma unroll
  for (int kk = 0; kk < 2; ++kk)
#pragma unroll
    for (int i = 0; i < 4; ++i)
      bhr[kk][i] = (i < ntcnt) ? *(const short8v*)&w1h[(((ntbase + i) * 8 + kk) * 64 + l) * 8]
                               : z8;

  // ---- GEMM1 ----
  floatx4 acc[4];
#pragma unroll
  for (int i = 0; i < 4; ++i) acc[i] = (floatx4){0.f, 0.f, 0.f, 0.f};

#pragma unroll
  for (int kt = 0; kt < 8; ++kt) {
    const int cur = kt & 1;
    short8v ah = (kt < 7) ? ga[cur] : a7h;
    if (kt < 5) ga[cur] = *(const short8v*)&ef[((tile * 7 + kt + 2) * 64 + l) * 8];
#pragma unroll
    for (int i = 0; i < 4; ++i) {
      if (i < ntcnt) {
        short8v cb = bhr[cur][i];
        if (kt < 6)
          bhr[cur][i] = *(const short8v*)&w1h[(((ntbase + i) * 8 + kt + 2) * 64 + l) * 8];
        acc[i] = __builtin_amdgcn_mfma_f32_16x16x32_bf16(ah, cb, acc[i], 0, 0, 0);
        if (kt == 7)
          acc[i] = __builtin_amdgcn_mfma_f32_16x16x32_bf16(a7l, cb, acc[i], 0, 0, 0);
      }
    }
    // drift limiter: raw barrier (no waitcnt drain) keeps same-ntg waves in
    // the same L1 window without killing the prefetch pipeline
    if (kt == 2 || kt == 5) __builtin_amdgcn_s_barrier();
  }

  // GEMM2 B prefetch: wave -> nt2 = ntg; ntg==3 also nt2=4
  const bool dual = (ntg == 3);
  short8v bra[2], brb[2];
  bra[0] = *(const short8v*)&w2h[((ntg * 7 + 0) * 64 + l) * 8];
  bra[1] = *(const short8v*)&w2h[((ntg * 7 + 1) * 64 + l) * 8];
  brb[0] = dual ? *(const short8v*)&w2h[((4 * 7 + 0) * 64 + l) * 8] : z8;
  brb[1] = dual ? *(const short8v*)&w2h[((4 * 7 + 1) * 64 + l) * 8] : z8;

  // ---- epilogue1: bias+relu -> A2[sub] frags (hi/lo) ----
#pragma unroll
  for (int i = 0; i < 4; ++i) {
    if (i < ntcnt) {
      int n = (ntbase + i) * 16 + (l & 15);
      float bias = (n < 200) ? b1[n] : 0.f;
      int kt2 = n >> 5, kg2 = (n >> 3) & 3, e = n & 7;
#pragma unroll
      for (int g = 0; g < 4; ++g) {
        float v = (n < 200) ? fmaxf(acc[i][g] + bias, 0.f) : 0.f;
        int m = (l >> 4) * 4 + g;
        u16 hi = f2bf(v), lo = f2bf(v - bf2f(hi));
        int pos = ((sub * 7 + kt2) * 64 + kg2 * 16 + m) * 8 + e;
        A2h[pos] = hi;
        A2l[pos] = lo;
      }
    }
  }
  if (ntg == 1 && l < 32) {  // zero k2 in [208,224) for own sub
    *(short8v*)&A2h[((sub * 7 + 6) * 64 + 32 + l) * 8] = z8;
    *(short8v*)&A2l[((sub * 7 + 6) * 64 + 32 + l) * 8] = z8;
  }
  __syncthreads();  // A2 complete

  // ---- GEMM2: wave (sub, nt2=ntg); ntg==3 also nt2=4 ----
  floatx4 acc2a = (floatx4){0.f, 0.f, 0.f, 0.f};
  floatx4 acc2b = (floatx4){0.f, 0.f, 0.f, 0.f};
#pragma unroll
  for (int kt = 0; kt < 7; ++kt) {
    short8v ah = *(const short8v*)&A2h[((sub * 7 + kt) * 64 + l) * 8];
    short8v al = *(const short8v*)&A2l[((sub * 7 + kt) * 64 + l) * 8];
    short8v ca = bra[kt & 1];
    if (kt < 5) bra[kt & 1] = *(const short8v*)&w2h[((ntg * 7 + kt + 2) * 64 + l) * 8];
    acc2a = __builtin_amdgcn_mfma_f32_16x16x32_bf16(ah, ca, acc2a, 0, 0, 0);
    acc2a = __builtin_amdgcn_mfma_f32_16x16x32_bf16(al, ca, acc2a, 0, 0, 0);
    if (dual) {
      short8v cb2 = brb[kt & 1];
      if (kt < 5) brb[kt & 1] = *(const short8v*)&w2h[((4 * 7 + kt + 2) * 64 + l) * 8];
      acc2b = __builtin_amdgcn_mfma_f32_16x16x32_bf16(ah, cb2, acc2b, 0, 0, 0);
      acc2b = __builtin_amdgcn_mfma_f32_16x16x32_bf16(al, cb2, acc2b, 0, 0, 0);
    }
  }

  // ---- epilogue2: bias+relu -> o2 [64][84] ----
  {
    int n = ntg * 16 + (l & 15);
    float bias = b2[n];
#pragma unroll
    for (int g = 0; g < 4; ++g) {
      int r2 = sub * 16 + (l >> 4) * 4 + g;
      o2[r2 * 84 + n] = fmaxf(acc2a[g] + bias, 0.f);
    }
    if (dual) {
      int n2 = 64 + (l & 15);
      float bias2 = b2[n2];
#pragma unroll
      for (int g = 0; g < 4; ++g) {
        int r2 = sub * 16 + (l >> 4) * 4 + g;
        o2[r2 * 84 + n2] = fmaxf(acc2b[g] + bias2, 0.f);
      }
    }
  }
  __syncthreads();  // o2 complete

  // ---- fc3: 128 threads, one (row, out) pair each ----
  if (tid < 128) {
    int r = tid >> 1, o = tid & 1;
    float a = b3[o];
    const float* orow = &o2[r * 84];
    const float* wrow = &w3[o * 80];
#pragma unroll
    for (int j = 0; j < 80; j += 4) {
      floatx4 xv = *(const floatx4*)&orow[j];
      floatx4 wv4 = *(const floatx4*)&wrow[j];
      a += xv[0] * wv4[0] + xv[1] * wv4[1] + xv[2] * wv4[2] + xv[3] * wv4[3];
    }
    out[(row0 + r) * 2 + o] = a;
  }
}

extern "C" void kernel_launch(void* const* d_in, const int* in_sizes, int n_in,
                              void* d_out, int out_size, void* d_ws, size_t ws_size,
                              hipStream_t stream) {
  const int* sf = (const int*)d_in[0];
  const float* dense = (const float*)d_in[1];
  const int* hist = (const int*)d_in[2];
  const float* W = (const float*)d_in[3];
  const float* w1 = (const float*)d_in[4];
  const float* b1 = (const float*)d_in[5];
  const float* w2 = (const float*)d_in[6];
  const float* b2 = (const float*)d_in[7];
  const float* w3 = (const float*)d_in[8];
  const float* b3 = (const float*)d_in[9];
  float* out = (float*)d_out;

  u16* w1h = (u16*)d_ws;
  u16* w2h = w1h + W1_ELEMS;
  u16* ef = w2h + W2_ELEMS;
  u16* hs = ef + EF_ELEMS;  // 2 MB

  prep_kernel<<<dim3(35 + 3584 + 1024), dim3(256), 0, stream>>>(
      w1, w2, W, sf, hist, dense, w1h, w2h, ef, hs);
  mlp_kernel<<<dim3(256), dim3(1024), 0, stream>>>(ef, hs, w1h, w2h, b1, b2, w3, b3, out);
}